// Round 9
// baseline (25.894 us; speedup 1.0000x reference)
//
#include <hip/hip_runtime.h>
#include <hip/hip_bf16.h>
#include <math.h>

#define S_LEN 2048
#define B_SZ  32
#define DIM   1024   // D == E == H == 1024
#define PTR   9      // min((0 + 9) * 1, 2047)
#define EPSV  1e-8f
#define NEGINF -1e9f
#define MROWS 320    // 32 dec rows + 288 enc rows
#define KZ    4      // k-split over blocks

typedef __attribute__((ext_vector_type(8)))  short  short8;
typedef __attribute__((ext_vector_type(16))) float  f32x16;

__device__ __forceinline__ short f2bf(float x) {
    __hip_bfloat16 h = __float2bfloat16(x);   // RNE; compiler emits v_cvt_pk_bf16_f32 pairs
    return *(short*)&h;
}

__device__ __forceinline__ float fast_tanh(float x) {
    float xc = fminf(fmaxf(x, -20.f), 20.f);
    float t = __expf(2.f * xc);
    return (t - 1.f) * __builtin_amdgcn_rcpf(t + 1.f);
}

// ---------------- D1: MFMA GEMM, in-register f32->bf16, k-split 4 over blocks ----------------
// Grid (32 nt, 10 mt, 4 kz). Block computes partial C_kz[mt*32+m][nt*32+n] over K=256,
// 4 waves x K=64 each, LDS reduce. Alpha one-hot + e/cnt zeroing folded in.
__global__ __launch_bounds__(256) void k_gemm(
    const float* __restrict__ input, const float* __restrict__ src,
    const float* __restrict__ Wdec, const float* __restrict__ Wenc,
    float* __restrict__ Cp, float* __restrict__ alpha, unsigned* __restrict__ ezero)
{
    const int nt = blockIdx.x;                   // 0..31
    const int mt = blockIdx.y;                   // 0..9 (0 = dec)
    const int kz = blockIdx.z;                   // 0..3
    const float* W     = (mt == 0) ? Wdec : Wenc;
    const float* Abase = (mt == 0) ? input : (src + (size_t)(mt - 1) * B_SZ * DIM);
    const int tid = threadIdx.x;
    const int w = tid >> 6, lane = tid & 63;
    const int r32 = lane & 31, kh = lane >> 5;
    const int kbase = kz * 256 + w * 64;
    const float* Ap = Abase + (size_t)r32 * DIM + kbase + kh * 8;
    const float* Bp = W + (size_t)(kbase + kh * 8) * DIM + nt * 32 + r32;

    // zero e (288 f32) + cnt (32 u32) for the tail's atomic combine
    if (nt == 0 && mt == 0 && kz == 0) {
        for (int i = tid; i < 320; i += 256) ezero[i] = 0u;
    }
    // alpha one-hot (2048x32; row s=8 -> floats [256,288) = 1), 64 blocks of kz==0
    if (kz == 0) {
        int bidl = mt * 32 + nt;
        if (bidl < 64) {
            int f = (bidl * 256 + tid) * 4;
            float val = (f >= 256 && f < 288) ? 1.0f : 0.0f;
            float4 o = {val, val, val, val};
            *(float4*)(alpha + f) = o;
        }
    }

    f32x16 acc;
    #pragma unroll
    for (int i = 0; i < 16; i++) acc[i] = 0.f;

    #pragma unroll
    for (int k = 0; k < 64; k += 16) {
        float4 a0 = *(const float4*)(Ap + k);
        float4 a1 = *(const float4*)(Ap + k + 4);
        const float* bp = Bp + (size_t)k * DIM;
        float bv0 = bp[0 * DIM], bv1 = bp[1 * DIM], bv2 = bp[2 * DIM], bv3 = bp[3 * DIM];
        float bv4 = bp[4 * DIM], bv5 = bp[5 * DIM], bv6 = bp[6 * DIM], bv7 = bp[7 * DIM];
        short8 af, bf;
        af[0] = f2bf(a0.x); af[1] = f2bf(a0.y); af[2] = f2bf(a0.z); af[3] = f2bf(a0.w);
        af[4] = f2bf(a1.x); af[5] = f2bf(a1.y); af[6] = f2bf(a1.z); af[7] = f2bf(a1.w);
        bf[0] = f2bf(bv0);  bf[1] = f2bf(bv1);  bf[2] = f2bf(bv2);  bf[3] = f2bf(bv3);
        bf[4] = f2bf(bv4);  bf[5] = f2bf(bv5);  bf[6] = f2bf(bv6);  bf[7] = f2bf(bv7);
        acc = __builtin_amdgcn_mfma_f32_32x32x16_bf16(af, bf, acc, 0, 0, 0);
    }

    __shared__ float red[4 * 64 * 17];
    const int base = (w * 64 + lane) * 17;
    #pragma unroll
    for (int r = 0; r < 16; r++) red[base + r] = acc[r];
    __syncthreads();
    // reduce the 4 wave k-slices; C/D layout: col = lane&31, row = (r&3)+8*(r>>2)+4*(lane>>5)
    const int L = tid & 63, g = tid >> 6;
    const int khL = L >> 5, col = L & 31;
    float* Cz = Cp + (size_t)kz * MROWS * DIM;
    #pragma unroll
    for (int j = 0; j < 4; j++) {
        int r = g * 4 + j;
        float s = red[(0 * 64 + L) * 17 + r] + red[(1 * 64 + L) * 17 + r]
                + red[(2 * 64 + L) * 17 + r] + red[(3 * 64 + L) * 17 + r];
        int row = (r & 3) + 8 * (r >> 2) + 4 * khL;
        Cz[(size_t)(mt * 32 + row) * DIM + nt * 32 + col] = s;
    }
}

// ---------------- D2: non-redundant energy + 8-block atomic combine + context ----------------
// Grid (32 b, 8 hs), 128 threads. Each block: partial energy over its 128 cols,
// atomicAdd into e[s,b] (coherence-point atomics, no cache fences), spin on per-b
// counter until all 8 partials land, atomic-load finals, softmax, context slice.
__global__ __launch_bounds__(128) void k_tail(
    const float* __restrict__ Cp,
    const unsigned char* __restrict__ mask,
    const float* __restrict__ bias, const float* __restrict__ v,
    const float* __restrict__ src, float* __restrict__ out,
    float* __restrict__ e, unsigned* __restrict__ cnt)
{
    const int b  = blockIdx.x;                 // 0..31
    const int hs = blockIdx.y;                 // 0..7
    const int tid = threadIdx.x;               // 0..127
    const int col = hs * 128 + tid;

    // prefetch src context values (independent of C)
    float sv[PTR];
    #pragma unroll
    for (int s = 0; s < PTR; s++)
        sv[s] = src[(size_t)(s * B_SZ + b) * DIM + col];

    // dec + bias at this col, summed over KZ partials
    float d = bias[col];
    #pragma unroll
    for (int p = 0; p < KZ; p++)
        d += Cp[(size_t)p * MROWS * DIM + (size_t)b * DIM + col];
    const float vvc = v[col];

    float ps[PTR];
    #pragma unroll
    for (int s = 0; s < PTR; s++) {
        const int row = 32 + s * 32 + b;
        float en = 0.f;
        #pragma unroll
        for (int p = 0; p < KZ; p++)
            en += Cp[(size_t)p * MROWS * DIM + (size_t)row * DIM + col];
        ps[s] = vvc * fast_tanh(d + en);
    }

    __shared__ float red[PTR][2];
    __shared__ float lds_e[PTR];
    const int lane = tid & 63, w = tid >> 6;
    #pragma unroll
    for (int s = 0; s < PTR; s++) {
        float val = ps[s];
        #pragma unroll
        for (int off = 32; off; off >>= 1) val += __shfl_down(val, off);
        if (lane == 0) red[s][w] = val;
    }
    __syncthreads();
    // partial energies -> coherence point
    if (tid < PTR) atomicAdd(&e[tid * B_SZ + b], red[tid][0] + red[tid][1]);
    asm volatile("s_waitcnt vmcnt(0)" ::: "memory");   // adds complete before counter bump
    __builtin_amdgcn_sched_barrier(0);
    __syncthreads();
    if (tid == 0) {
        __hip_atomic_fetch_add(&cnt[b], 1u, __ATOMIC_RELAXED, __HIP_MEMORY_SCOPE_AGENT);
        int guard = 0;
        while (__hip_atomic_load(&cnt[b], __ATOMIC_RELAXED, __HIP_MEMORY_SCOPE_AGENT) < 8u) {
            __builtin_amdgcn_s_sleep(1);
            if (++guard > (1 << 22)) break;            // bail rather than hang
        }
    }
    __syncthreads();
    if (tid < PTR) {
        float ev = __hip_atomic_load(&e[tid * B_SZ + b], __ATOMIC_RELAXED, __HIP_MEMORY_SCOPE_AGENT);
        if (mask[(size_t)tid * B_SZ + b]) ev = NEGINF;
        lds_e[tid] = ev;
    }
    __syncthreads();
    // softmax (identical in every thread), then context slice
    float es[PTR], mx = -INFINITY;
    #pragma unroll
    for (int s = 0; s < PTR; s++) { es[s] = lds_e[s]; mx = fmaxf(mx, es[s]); }
    float tot = 0.f;
    #pragma unroll
    for (int s = 0; s < PTR; s++) { es[s] = __expf(es[s] - mx) + EPSV; tot += es[s]; }
    const float inv = 1.0f / tot;
    float acc = 0.f;
    #pragma unroll
    for (int s = 0; s < PTR; s++) acc += es[s] * inv * sv[s];
    out[(size_t)b * DIM + col] = acc;
}

extern "C" void kernel_launch(void* const* d_in, const int* in_sizes, int n_in,
                              void* d_out, int out_size, void* d_ws, size_t ws_size,
                              hipStream_t stream) {
    const float* input = (const float*)d_in[0];
    const float* src   = (const float*)d_in[1];
    const unsigned char* mask = (const unsigned char*)d_in[2];
    const float* Wdec  = (const float*)d_in[3];
    const float* Wenc  = (const float*)d_in[4];
    const float* bias  = (const float*)d_in[5];
    const float* v     = (const float*)d_in[6];
    float* out   = (float*)d_out;
    float* alpha = out + B_SZ * DIM;

    float* Cp = (float*)d_ws;                         // KZ x 320*1024 f32 partials
    float* e  = Cp + (size_t)KZ * MROWS * DIM;        // 288 f32
    unsigned* cnt = (unsigned*)(e + 288);             // 32 u32

    k_gemm<<<dim3(32, 10, KZ), 256, 0, stream>>>(input, src, Wdec, Wenc, Cp, alpha, (unsigned*)e);
    k_tail<<<dim3(B_SZ, 8), 128, 0, stream>>>(Cp, mask, bias, v, src, out, e, cnt);
}

// Round 10
// 19.764 us; speedup vs baseline: 1.3102x; 1.3102x over previous
//
#include <hip/hip_runtime.h>
#include <hip/hip_bf16.h>
#include <math.h>

#define S_LEN 2048
#define B_SZ  32
#define DIM   1024   // D == E == H == 1024
#define PTR   9      // min((0 + 9) * 1, 2047)
#define EPSV  1e-8f
#define NEGINF -1e9f
#define MROWS 320    // 32 dec rows + 288 enc rows
#define KZ    2      // k-split over blocks (R7/R8 proven)

typedef __attribute__((ext_vector_type(8)))  short  short8;
typedef __attribute__((ext_vector_type(16))) float  f32x16;

__device__ __forceinline__ short f2bf(float x) {
    __hip_bfloat16 h = __float2bfloat16(x);   // RNE; compiler emits v_cvt_pk_bf16_f32 pairs
    return *(short*)&h;
}
__device__ __forceinline__ float bf2f(ushort u) {
    return __uint_as_float(((unsigned)u) << 16);
}

__device__ __forceinline__ float fast_tanh(float x) {
    float xc = fminf(fmaxf(x, -20.f), 20.f);
    float t = __expf(2.f * xc);
    return (t - 1.f) * __builtin_amdgcn_rcpf(t + 1.f);
}

// ---------------- D1: MFMA GEMM, in-register f32->bf16, k-split 2, bf16 C ----------------
// Grid (32 nt, 10 mt, 2 kz). Block computes partial C_kz[mt*32+m][nt*32+n] over K=512,
// 4 waves x K=128 each, LDS reduce, store C as bf16. Alpha one-hot folded into kz==0.
__global__ __launch_bounds__(256) void k_gemm(
    const float* __restrict__ input, const float* __restrict__ src,
    const float* __restrict__ Wdec, const float* __restrict__ Wenc,
    ushort* __restrict__ Cp, float* __restrict__ alpha)
{
    const int nt = blockIdx.x;                   // 0..31
    const int mt = blockIdx.y;                   // 0..9 (0 = dec)
    const int kz = blockIdx.z;                   // 0..1
    const float* W     = (mt == 0) ? Wdec : Wenc;
    const float* Abase = (mt == 0) ? input : (src + (size_t)(mt - 1) * B_SZ * DIM);
    const int tid = threadIdx.x;
    const int w = tid >> 6, lane = tid & 63;
    const int r32 = lane & 31, kh = lane >> 5;
    const int kbase = kz * 512 + w * 128;
    const float* Ap = Abase + (size_t)r32 * DIM + kbase + kh * 8;
    const float* Bp = W + (size_t)(kbase + kh * 8) * DIM + nt * 32 + r32;

    // alpha one-hot (2048x32; row s=8 -> floats [256,288) = 1), 64 blocks of kz==0
    if (kz == 0) {
        int bidl = mt * 32 + nt;
        if (bidl < 64) {
            int f = (bidl * 256 + tid) * 4;
            float val = (f >= 256 && f < 288) ? 1.0f : 0.0f;
            float4 o = {val, val, val, val};
            *(float4*)(alpha + f) = o;
        }
    }

    f32x16 acc;
    #pragma unroll
    for (int i = 0; i < 16; i++) acc[i] = 0.f;

    #pragma unroll 4
    for (int k = 0; k < 128; k += 16) {
        float4 a0 = *(const float4*)(Ap + k);
        float4 a1 = *(const float4*)(Ap + k + 4);
        const float* bp = Bp + (size_t)k * DIM;
        float bv0 = bp[0 * DIM], bv1 = bp[1 * DIM], bv2 = bp[2 * DIM], bv3 = bp[3 * DIM];
        float bv4 = bp[4 * DIM], bv5 = bp[5 * DIM], bv6 = bp[6 * DIM], bv7 = bp[7 * DIM];
        short8 af, bf;
        af[0] = f2bf(a0.x); af[1] = f2bf(a0.y); af[2] = f2bf(a0.z); af[3] = f2bf(a0.w);
        af[4] = f2bf(a1.x); af[5] = f2bf(a1.y); af[6] = f2bf(a1.z); af[7] = f2bf(a1.w);
        bf[0] = f2bf(bv0);  bf[1] = f2bf(bv1);  bf[2] = f2bf(bv2);  bf[3] = f2bf(bv3);
        bf[4] = f2bf(bv4);  bf[5] = f2bf(bv5);  bf[6] = f2bf(bv6);  bf[7] = f2bf(bv7);
        acc = __builtin_amdgcn_mfma_f32_32x32x16_bf16(af, bf, acc, 0, 0, 0);
    }

    __shared__ float red[4 * 64 * 17];
    const int base = (w * 64 + lane) * 17;
    #pragma unroll
    for (int r = 0; r < 16; r++) red[base + r] = acc[r];
    __syncthreads();
    // reduce the 4 wave k-slices; C/D layout: col = lane&31, row = (r&3)+8*(r>>2)+4*(lane>>5)
    const int L = tid & 63, g = tid >> 6;
    const int khL = L >> 5, col = L & 31;
    ushort* Cz = Cp + (size_t)kz * MROWS * DIM;
    #pragma unroll
    for (int j = 0; j < 4; j++) {
        int r = g * 4 + j;
        float s = red[(0 * 64 + L) * 17 + r] + red[(1 * 64 + L) * 17 + r]
                + red[(2 * 64 + L) * 17 + r] + red[(3 * 64 + L) * 17 + r];
        int row = (r & 3) + 8 * (r >> 2) + 4 * khL;
        Cz[(size_t)(mt * 32 + row) * DIM + nt * 32 + col] = (ushort)f2bf(s);
    }
}

// ---------------- D2: energy (redundant per h-slice) + softmax + sliced context ----------------
// Grid (32 b, 4 hs), 256 threads. Each block computes full-H energy+softmax for its b
// (bf16 C rows, 4x redundant), then threads 0..63 write the 256-col context slice.
__global__ __launch_bounds__(256) void k_tail(
    const ushort* __restrict__ Cp,
    const unsigned char* __restrict__ mask,
    const float* __restrict__ bias, const float* __restrict__ v,
    const float* __restrict__ src, float* __restrict__ out)
{
    const int b  = blockIdx.x;                 // 0..31
    const int hs = blockIdx.y;                 // 0..3
    const int tid = threadIdx.x;
    const int h = tid * 4;
    const ushort* C0 = Cp;
    const ushort* C1 = Cp + (size_t)MROWS * DIM;

    // hoisted src loads for this block's 256-col context slice (threads 0..63)
    const int hc = hs * 256 + (tid & 63) * 4;
    float4 sv[PTR];
    if (tid < 64) {
        #pragma unroll
        for (int s = 0; s < PTR; s++)
            sv[s] = *(const float4*)(src + (size_t)(s * B_SZ + b) * DIM + hc);
    }

    ushort4 dau = *(const ushort4*)(C0 + (size_t)b * DIM + h);
    ushort4 dbu = *(const ushort4*)(C1 + (size_t)b * DIM + h);
    float4 bb = *(const float4*)(bias + h);
    float4 vv = *(const float4*)(v + h);
    const float bx = bf2f(dau.x) + bf2f(dbu.x) + bb.x;
    const float by = bf2f(dau.y) + bf2f(dbu.y) + bb.y;
    const float bz = bf2f(dau.z) + bf2f(dbu.z) + bb.z;
    const float bw = bf2f(dau.w) + bf2f(dbu.w) + bb.w;
    float ps[PTR];
    #pragma unroll
    for (int s = 0; s < PTR; s++) {
        const size_t row = (size_t)(32 + s * 32 + b) * DIM + h;
        ushort4 e0 = *(const ushort4*)(C0 + row);
        ushort4 e1 = *(const ushort4*)(C1 + row);
        ps[s] = vv.x * fast_tanh(bx + bf2f(e0.x) + bf2f(e1.x))
              + vv.y * fast_tanh(by + bf2f(e0.y) + bf2f(e1.y))
              + vv.z * fast_tanh(bz + bf2f(e0.z) + bf2f(e1.z))
              + vv.w * fast_tanh(bw + bf2f(e0.w) + bf2f(e1.w));
    }
    __shared__ float red[PTR][4];
    __shared__ float wgt[PTR];
    const int lane = tid & 63, wv = tid >> 6;
    #pragma unroll
    for (int s = 0; s < PTR; s++) {
        float val = ps[s];
        #pragma unroll
        for (int off = 32; off; off >>= 1) val += __shfl_down(val, off);
        if (lane == 0) red[s][wv] = val;
    }
    __syncthreads();
    if (tid == 0) {
        float es[PTR];
        float mx = -INFINITY;
        #pragma unroll
        for (int s = 0; s < PTR; s++) {
            float e = red[s][0] + red[s][1] + red[s][2] + red[s][3];
            if (mask[(size_t)s * B_SZ + b]) e = NEGINF;
            es[s] = e; mx = fmaxf(mx, e);
        }
        float tot = 0.f;
        #pragma unroll
        for (int s = 0; s < PTR; s++) { es[s] = __expf(es[s] - mx) + EPSV; tot += es[s]; }
        float inv = 1.0f / tot;
        #pragma unroll
        for (int s = 0; s < PTR; s++) wgt[s] = es[s] * inv;
    }
    __syncthreads();
    if (tid < 64) {
        float4 acc = {0.f, 0.f, 0.f, 0.f};
        #pragma unroll
        for (int s = 0; s < PTR; s++) {
            float wq = wgt[s];
            acc.x += wq * sv[s].x; acc.y += wq * sv[s].y;
            acc.z += wq * sv[s].z; acc.w += wq * sv[s].w;
        }
        *(float4*)(out + (size_t)b * DIM + hc) = acc;
    }
}

extern "C" void kernel_launch(void* const* d_in, const int* in_sizes, int n_in,
                              void* d_out, int out_size, void* d_ws, size_t ws_size,
                              hipStream_t stream) {
    const float* input = (const float*)d_in[0];
    const float* src   = (const float*)d_in[1];
    const unsigned char* mask = (const unsigned char*)d_in[2];
    const float* Wdec  = (const float*)d_in[3];
    const float* Wenc  = (const float*)d_in[4];
    const float* bias  = (const float*)d_in[5];
    const float* v     = (const float*)d_in[6];
    float* out   = (float*)d_out;
    float* alpha = out + B_SZ * DIM;

    ushort* Cp = (ushort*)d_ws;                 // KZ x 320*1024 bf16 partials

    k_gemm<<<dim3(32, 10, KZ), 256, 0, stream>>>(input, src, Wdec, Wenc, Cp, alpha);
    k_tail<<<dim3(B_SZ, 4), 256, 0, stream>>>(Cp, mask, bias, v, src, out);
}